// Round 3
// baseline (11326.517 us; speedup 1.0000x reference)
//
#include <hip/hip_runtime.h>
#include <hip/hip_bf16.h>

// ESN scan: h_{t+1} = 0.1*h_t + 0.9*tanh(x_t @ Win^T + b + h_t @ W^T)
// B=32, T=1000, D=64, H=1024.
//
// R6: probe-validated XCD-local scan.
//  - 8 groups x 32 blocks; group g owns batches [4g,4g+4). Each block owns
//    32 h-cols; W fragments register-resident (17 x uint4v / wave, 2Nx2K).
//  - Grouping by HW_REG_XCC_ID with runtime symmetry check (32 blocks/XCD).
//  - NEW: LOCAL cache semantics (plain write-through store + sc0 load
//    meeting in the XCD L2) are VERIFIED at runtime by a fence-free
//    two-round handshake probe that mimics the scan's exact access pattern
//    (incl. repeated-line reads). Probe failure or asymmetric placement =>
//    fallback to sc0 sc1 (L3) protocol, which is R3's proven-correct path.
//    All probe polls are bounded => no configuration can deadlock.
//  - R5 lesson: 192-VGPR pad likely made cooperative launch REJECT the
//    grid (zeros output, absmax err exactly 1.0 = max|tanh|). R6: no pad,
//    VGPR ~170 via __launch_bounds__(256,2); host checks the launch error
//    and falls back to a plain launch.

#define B_    32
#define T_    1000
#define D_    64
#define H_    1024
#define GRID  256
#define NTHR  256
#define LRATE 0.9f
#define NSLOT 32

#define ROWS  5              // 4 batch rows + 1 zero row (A rows 4..15)
#define RLEN  1088           // K extent: 1024 h + 64 x
#define BUFE  (ROWS * RLEN)  // 5440 bf16 per buffer

// ws layout (harness memsets ws each dispatch; R3 relied on this too):
//   [0,1024)        device barrier arrive flags (256 ints)
//   [1024,1056)     per-XCD block counters (8 ints)
//   [1056,1060)     badflag (probe verdict)
//   [8192,40960)    probe region: (g*32+slot)*128B  {data[2] @+0, flag @+64}
//   [40960,73728)   per-group flag regions: 32 flags * 128B, stride 4096
//   [73728,335872)  per-group h buffers: 2*5440*2B, stride 32768
#define OFF_CNT      1024
#define OFF_BAD      1056
#define OFF_PROBE    8192
#define PROBE_STRIDE 128
#define OFF_FLAGS    40960
#define FLAG_STRIDE  4096
#define OFF_HB       73728
#define HB_STRIDE    32768

typedef __bf16 bf16_t;
typedef __bf16 bf16x8 __attribute__((ext_vector_type(8)));
typedef float  f32x4  __attribute__((ext_vector_type(4)));
typedef float  f32x2  __attribute__((ext_vector_type(2)));
typedef unsigned uint4v __attribute__((ext_vector_type(4)));

__device__ __forceinline__ unsigned pack_bf16(float a, float b) {
    unsigned short lo = __builtin_bit_cast(unsigned short, (bf16_t)a);
    unsigned short hi = __builtin_bit_cast(unsigned short, (bf16_t)b);
    return (unsigned)lo | ((unsigned)hi << 16);
}

// Device-wide barrier with release/acquire agent fences (wbl2 / inv).
__device__ __forceinline__ void device_barrier(int* arrive, int bid, int tid, int target) {
    __builtin_amdgcn_fence(__ATOMIC_RELEASE, "agent");
    __syncthreads();
    if (tid < 64) {
        if (tid == 0)
            __hip_atomic_store(&arrive[bid], target, __ATOMIC_RELAXED, __HIP_MEMORY_SCOPE_AGENT);
        for (;;) {
            int v0 = __hip_atomic_load(&arrive[tid],       __ATOMIC_RELAXED, __HIP_MEMORY_SCOPE_AGENT);
            int v1 = __hip_atomic_load(&arrive[tid + 64],  __ATOMIC_RELAXED, __HIP_MEMORY_SCOPE_AGENT);
            int v2 = __hip_atomic_load(&arrive[tid + 128], __ATOMIC_RELAXED, __HIP_MEMORY_SCOPE_AGENT);
            int v3 = __hip_atomic_load(&arrive[tid + 192], __ATOMIC_RELAXED, __HIP_MEMORY_SCOPE_AGENT);
            if (__all((v0 >= target) & (v1 >= target) & (v2 >= target) & (v3 >= target))) break;
            __builtin_amdgcn_s_sleep(1);
        }
    }
    __syncthreads();
    __builtin_amdgcn_fence(__ATOMIC_ACQUIRE, "agent");
}

// LOCAL=true : plain store (write-through L1 -> XCD L2) + sc0 load (L1
//              bypass, reads XCD L2). Validated at runtime by the probe.
// LOCAL=false: sc0 sc1 both ways (L3 coherence point) - R3's protocol.
template<bool LOCAL>
__device__ __forceinline__ void ld16(uint4v& r, const bf16_t* p) {
    if constexpr (LOCAL)
        asm volatile("global_load_dwordx4 %0, %1, off sc0" : "=&v"(r) : "v"(p) : "memory");
    else
        asm volatile("global_load_dwordx4 %0, %1, off sc0 sc1" : "=&v"(r) : "v"(p) : "memory");
}
template<bool LOCAL>
__device__ __forceinline__ void st32(void* p, unsigned v) {
    if constexpr (LOCAL)
        asm volatile("global_store_dword %0, %1, off" :: "v"(p), "v"(v) : "memory");
    else
        asm volatile("global_store_dword %0, %1, off sc0 sc1" :: "v"(p), "v"(v) : "memory");
}
template<bool LOCAL>
__device__ __forceinline__ int ldflag(const int* p) {
    int v;
    if constexpr (LOCAL)
        asm volatile("global_load_dword %0, %1, off sc0\n\ts_waitcnt vmcnt(0)"
                     : "=&v"(v) : "v"(p) : "memory");
    else
        asm volatile("global_load_dword %0, %1, off sc0 sc1\n\ts_waitcnt vmcnt(0)"
                     : "=&v"(v) : "v"(p) : "memory");
    return v;
}

template<bool LOCAL>
__device__ __forceinline__ void scan_loop(
    uint4v (&breg)[17],
    const bf16_t* Ab0, const bf16_t* Ab1,
    bf16_t* buf0, bf16_t* buf1,
    int* flags, int slot, int h0,
    const float* xp, int xb, int xd,
    float* outp, float bias_c,
    float* lds, int tid, int lane, int wv)
{
    const int quad = lane >> 4;
    const int mcol = lane & 15;
    const int fb   = (tid >> 5) & 3;
    const int fcw  = tid & 31;
    const int fn   = fcw >> 4, fcc = fcw & 15;
    int*       myflag = flags + slot * 32;
    const int* pollp  = flags + (lane & 31) * 32;
    float hp = 0.f;

    #pragma unroll 1
    for (int t = 0; t < T_; ++t) {
        const bf16_t* Ab   = (t & 1) ? Ab1 : Ab0;
        bf16_t*       nxtb = (t & 1) ? buf0 : buf1;

        // x_{t+1} prefetch (slot-0 block, waves 2-3): latency hides under
        // the A-load + MFMA phase.
        f32x2 xv = {0.f, 0.f};
        const bool doX = (slot == 0) && (tid >= 128) && (t + 1 < T_);
        if (doX)
            asm volatile("global_load_dwordx2 %0, %1, off" : "=v"(xv) : "v"(xp) : "memory");

        // A-fragments: 17 back-to-back 16B loads -> one L2 (LOCAL) / L3 RT.
        uint4v a0,a1,a2,a3,a4,a5,a6,a7,a8,a9,a10,a11,a12,a13,a14,a15,a16;
        ld16<LOCAL>(a0,  Ab +  0*32); ld16<LOCAL>(a1,  Ab +  1*32);
        ld16<LOCAL>(a2,  Ab +  2*32); ld16<LOCAL>(a3,  Ab +  3*32);
        ld16<LOCAL>(a4,  Ab +  4*32); ld16<LOCAL>(a5,  Ab +  5*32);
        ld16<LOCAL>(a6,  Ab +  6*32); ld16<LOCAL>(a7,  Ab +  7*32);
        ld16<LOCAL>(a8,  Ab +  8*32); ld16<LOCAL>(a9,  Ab +  9*32);
        ld16<LOCAL>(a10, Ab + 10*32); ld16<LOCAL>(a11, Ab + 11*32);
        ld16<LOCAL>(a12, Ab + 12*32); ld16<LOCAL>(a13, Ab + 13*32);
        ld16<LOCAL>(a14, Ab + 14*32); ld16<LOCAL>(a15, Ab + 15*32);
        ld16<LOCAL>(a16, Ab + 16*32);
        asm volatile("s_waitcnt vmcnt(0)"
                     : "+v"(a0),"+v"(a1),"+v"(a2),"+v"(a3),"+v"(a4),"+v"(a5),
                       "+v"(a6),"+v"(a7),"+v"(a8),"+v"(a9),"+v"(a10),"+v"(a11),
                       "+v"(a12),"+v"(a13),"+v"(a14),"+v"(a15),"+v"(a16),
                       "+v"(xv)
                     :: "memory");

        // 17 MFMA, 4 interleaved accumulator chains.
        f32x4 acc0 = {0.f,0.f,0.f,0.f}, acc1 = acc0, acc2 = acc0, acc3 = acc0;
        #define AM(reg, idx, acc) \
            acc = __builtin_amdgcn_mfma_f32_16x16x32_bf16( \
                __builtin_bit_cast(bf16x8, reg), \
                __builtin_bit_cast(bf16x8, breg[idx]), acc, 0, 0, 0);
        AM(a0,0,acc0)   AM(a1,1,acc1)   AM(a2,2,acc2)   AM(a3,3,acc3)
        AM(a4,4,acc0)   AM(a5,5,acc1)   AM(a6,6,acc2)   AM(a7,7,acc3)
        AM(a8,8,acc0)   AM(a9,9,acc1)   AM(a10,10,acc2) AM(a11,11,acc3)
        AM(a12,12,acc0) AM(a13,13,acc1) AM(a14,14,acc2) AM(a15,15,acc3)
        AM(a16,16,acc0)
        #undef AM
        f32x4 acc = (acc0 + acc1) + (acc2 + acc3);

        // Cross-wave K-half reduce via LDS. C/D: col=lane&15, row=quad*4+i.
        #pragma unroll
        for (int i = 0; i < 4; ++i)
            lds[wv * 256 + (quad * 4 + i) * 16 + mcol] = acc[i];
        __syncthreads();

        float hn = 0.f;
        if (tid < 128) {
            // wave (n_=fn,kh=0) = region fn; wave (n_=fn,kh=1) = region fn+2
            float s  = lds[fn * 256 + fb * 16 + fcc]
                     + lds[(fn + 2) * 256 + fb * 16 + fcc];
            float u  = s + bias_c;
            hn = (1.f - LRATE) * hp + LRATE * tanhf(u);
            hp = hn;
            unsigned hbits = (unsigned)__builtin_bit_cast(unsigned short, (bf16_t)hn);
            unsigned hi    = __shfl_down(hbits, 1);
            if (!(tid & 1))
                st32<LOCAL>(nxtb + fb * RLEN + h0 + fcw, hbits | (hi << 16));
        } else if (doX) {
            st32<LOCAL>(nxtb + xb * RLEN + H_ + xd, pack_bf16(xv[0], xv[1]));
            xp += D_;
        }

        if (t + 1 < T_) {
            // Drain h/x stores (ack from coherence point), then publish.
            asm volatile("s_waitcnt vmcnt(0)" ::: "memory");
            __syncthreads();
            if (tid == 0)
                st32<LOCAL>(myflag, (unsigned)(t + 1));
            if (tid < 128) outp[(size_t)t * H_] = hn;   // off critical path
            const int target = t + 1;
            for (;;) {
                int v = ldflag<LOCAL>(pollp);
                if (__all(v >= target)) break;
            }
        } else {
            if (tid < 128) outp[(size_t)t * H_] = hn;
        }
    }
}

__global__ __launch_bounds__(NTHR, 2) void esn_scan(
    const float* __restrict__ x,     // [B, T, D]
    const float* __restrict__ Win,   // [H, D]
    const float* __restrict__ bias,  // [H]
    const float* __restrict__ W,     // [H, H]
    float* __restrict__ out,         // [B, T, H]
    unsigned char* wsb)
{
    __shared__ float lds[1024];
    __shared__ int slot_sh;

    int* darr = (int*)wsb;
    int* cnt  = (int*)(wsb + OFF_CNT);
    int* badp = (int*)(wsb + OFF_BAD);

    unsigned xcd;
    asm volatile("s_getreg_b32 %0, hwreg(HW_REG_XCC_ID)" : "=s"(xcd));
    xcd &= 7;

    const int tid  = threadIdx.x;
    const int bid  = blockIdx.x;
    const int lane = tid & 63;
    const int wv   = tid >> 6;

    if (tid == 0) slot_sh = atomicAdd(&cnt[xcd], 1);
    __syncthreads();
    const int slot_raw = slot_sh;

    device_barrier(darr, bid, tid, 1);

    // Symmetry: did every XCD get exactly 32 blocks?
    bool sym;
    {
        int c = __hip_atomic_load(&cnt[lane & 7], __ATOMIC_RELAXED, __HIP_MEMORY_SCOPE_AGENT);
        sym = __all(c == NSLOT);
    }
    const int g  = sym ? (int)xcd : (bid & 7);
    const int s  = sym ? slot_raw : (bid >> 3);
    const int h0 = s * 32;

    // ---- LOCAL-coherence probe (fence-free, mimics scan semantics) ----
    // Ring: block (g,s) produces for (g,s-1), consumes from (g,s+1).
    // Two rounds; round 2 re-reads the same flag/data lines (catches
    // consumer-L1 staleness). Bounded polls => never deadlocks.
    if (tid == 0) {
        unsigned* pd = (unsigned*)(wsb + OFF_PROBE + ((size_t)g * 32 + s) * PROBE_STRIDE);
        unsigned* pf = pd + 16;   // +64B
        unsigned* nd = (unsigned*)(wsb + OFF_PROBE + ((size_t)g * 32 + ((s + 1) & 31)) * PROBE_STRIDE);
        unsigned* nf = nd + 16;
        int bad = 0;
        for (int round = 1; round <= 2 && !bad; ++round) {
            unsigned val = 0xA5000000u + ((unsigned)round << 16) + (unsigned)s;
            st32<true>(pd + (round & 1), val);
            asm volatile("s_waitcnt vmcnt(0)" ::: "memory");
            st32<true>(pf, (unsigned)round);
            unsigned fv = 0; int iters = 0;
            for (;;) {
                fv = (unsigned)ldflag<true>((const int*)nf);
                if (fv >= (unsigned)round) break;
                if (++iters > 100000) { bad = 1; break; }
            }
            if (!bad) {
                unsigned dv = (unsigned)ldflag<true>((const int*)(nd + (round & 1)));
                unsigned expect = 0xA5000000u + ((unsigned)round << 16) + (unsigned)((s + 1) & 31);
                if (dv != expect) bad = 1;
            }
        }
        if (bad) atomicOr(badp, 1);
    }

    device_barrier(darr, bid, tid, 2);

    int badv = __hip_atomic_load(badp, __ATOMIC_RELAXED, __HIP_MEMORY_SCOPE_AGENT);
    const bool local = sym && (badv == 0);

    int*    flags = (int*)(wsb + OFF_FLAGS + (size_t)g * FLAG_STRIDE);
    bf16_t* hb    = (bf16_t*)(wsb + OFF_HB + (size_t)g * HB_STRIDE);
    bf16_t* buf0  = hb;
    bf16_t* buf1  = hb + BUFE;

    // ---------------- init ----------------
    // Zero buf0 h-region (rows 0-3, k<1024) + zero-row 4 of BOTH buffers.
    {
        unsigned* hb32 = (unsigned*)hb;              // u32 view, row stride 544
        unsigned gi = (unsigned)s * NTHR + tid;
        if (gi < 2048)            hb32[(gi >> 9) * 544 + (gi & 511)] = 0;
        else if (gi < 2592)       hb32[4 * 544 + (gi - 2048)] = 0;
        else if (gi < 3136)       hb32[2720 + 4 * 544 + (gi - 2592)] = 0;
        if (s == 0) {             // stage x_0 into buf0 x-region
            int b = tid >> 6, d = tid & 63;
            float v = x[(size_t)(4 * g + b) * (T_ * D_) + d];
            hb[b * RLEN + H_ + d] = (bf16_t)v;
        }
    }

    // B-fragments: W rows [h0,h0+32) (+ Win for k>=1024), bf16, registers.
    const int n_   = wv & 1;          // N-tile (16 cols)
    const int kh   = wv >> 1;         // K half [kh*544, kh*544+544)
    const int quad = lane >> 4;
    const int mcol = lane & 15;
    const int col  = h0 + n_ * 16 + mcol;

    uint4v breg[17];
    for (int kc = 0; kc < 17; ++kc) {
        int kb = kh * 544 + kc * 32 + quad * 8;
        float v[8];
        #pragma unroll
        for (int j = 0; j < 8; ++j) {
            int k = kb + j;
            v[j] = (k < H_) ? W[(size_t)col * H_ + k]
                            : Win[col * D_ + (k - H_)];
        }
        uint4v p;
        p[0] = pack_bf16(v[0], v[1]); p[1] = pack_bf16(v[2], v[3]);
        p[2] = pack_bf16(v[4], v[5]); p[3] = pack_bf16(v[6], v[7]);
        breg[kc] = p;
    }

    // A-fragment base: row = batch (lane&15), rows >=4 clamp to zero-row 4.
    const int r    = mcol;
    const int rr   = (r < 4) ? r : 4;
    const int aoff = rr * RLEN + kh * 544 + quad * 8;
    const bf16_t* Ab0 = buf0 + aoff;
    const bf16_t* Ab1 = buf1 + aoff;

    // Finisher state (waves 0-1): one (batch, col) per thread.
    const int fb  = (tid >> 5) & 3;
    const int fcw = tid & 31;
    const float bias_c = bias[h0 + fcw];
    float* outp = out + (size_t)(4 * g + fb) * (T_ * H_) + h0 + fcw;

    // x-prefetch state (slot-0 block, waves 2-3): 2 floats/thread/step.
    const int t2 = tid & 127;
    const int xb = t2 >> 5, xd = (t2 & 31) * 2;
    const float* xp = x + (size_t)(4 * g + xb) * (T_ * D_) + D_ + xd; // t=1

    device_barrier(darr, bid, tid, 3);   // flushes init stores (wbl2)

    // ---------------- scan ----------------
    if (local)
        scan_loop<true >(breg, Ab0, Ab1, buf0, buf1, flags, s, h0,
                         xp, xb, xd, outp, bias_c, lds, tid, lane, wv);
    else
        scan_loop<false>(breg, Ab0, Ab1, buf0, buf1, flags, s, h0,
                         xp, xb, xd, outp, bias_c, lds, tid, lane, wv);
}

extern "C" void kernel_launch(void* const* d_in, const int* in_sizes, int n_in,
                              void* d_out, int out_size, void* d_ws, size_t ws_size,
                              hipStream_t stream) {
    (void)in_sizes; (void)n_in; (void)out_size; (void)ws_size;
    const float* x    = (const float*)d_in[0];
    const float* Win  = (const float*)d_in[1];
    const float* bias = (const float*)d_in[2];
    const float* W    = (const float*)d_in[3];
    float*       out  = (float*)d_out;
    void*        ws   = d_ws;

    void* args[] = { (void*)&x, (void*)&Win, (void*)&bias, (void*)&W, (void*)&out, (void*)&ws };
    hipError_t e = hipLaunchCooperativeKernel((const void*)esn_scan, dim3(GRID), dim3(NTHR), args, 0, stream);
    if (e != hipSuccess) {
        // 256 blocks at >=2 blocks/CU occupancy are always co-resident on
        // 256 CUs; the spin protocol then still completes.
        hipLaunchKernelGGL(esn_scan, dim3(GRID), dim3(NTHR), 0, stream,
                           x, Win, bias, W, out, (unsigned char*)ws);
    }
}

// Round 4
// 2997.465 us; speedup vs baseline: 3.7787x; 3.7787x over previous
//
#include <hip/hip_runtime.h>
#include <hip/hip_bf16.h>

// ESN scan: h_{t+1} = 0.1*h_t + 0.9*tanh(x_t @ Win^T + b + h_t @ W^T)
// B=32, T=1000, D=64, H=1024.
//
// R7: forced-symmetric XCD-local scan.
// R6 post-mortem: WRITE_SIZE 204MB == R3's 202MB => scan ran FALLBACK;
// 11.3ms = fallback scan (~5.3ms) + ~6ms one-time probe timeout (100k
// stale-clean L2 polls after cross-XCD ring neighbors). Placement was
// asymmetric because small blocks get packed per-CU. Fixes:
//  - 88KB DYNAMIC shared (hipFuncSetAttribute) -> 1 block/CU -> 256 coop
//    blocks on 256 CUs -> exactly 32 blocks/XCD, deterministically.
//    Launch ladder: coop+88KB -> coop+0 -> plain (no config fails hard).
//  - Dense flags: one 128B line per group (32 x 4B). Poll = ONE coalesced
//    line-load per wave per iteration (R6: 32 lines x 128B stride).
//  - Probe gated on sym, timeout 100k -> 8k iters (<=0.4ms worst case).
// Scan protocol unchanged from R6 (passed): LOCAL = plain write-through
// stores + sc0 loads meeting in the XCD's L2; FALLBACK = sc0 sc1 (L3),
// R3's proven path. Probe validates LOCAL semantics before use.

#define B_    32
#define T_    1000
#define D_    64
#define H_    1024
#define GRID  256
#define NTHR  256
#define LRATE 0.9f
#define NSLOT 32

#define ROWS  5              // 4 batch rows + 1 zero row (A rows 4..15)
#define RLEN  1088           // K extent: 1024 h + 64 x
#define BUFE  (ROWS * RLEN)  // 5440 bf16 per buffer

// ws layout (harness memsets ws each dispatch):
//   [0,1024)        device barrier arrive flags (256 ints)
//   [1024,1056)     per-XCD block counters (8 ints)
//   [1056,1060)     badflag (probe verdict)
//   [8192,40960)    probe region: (g*32+slot)*128B {data[2] @+0, flag @+64}
//   [40960,43008)   per-group flag lines: 32 ints dense, 256B stride
//   [73728,335872)  per-group h buffers: 2*5440*2B, stride 32768
#define OFF_CNT      1024
#define OFF_BAD      1056
#define OFF_PROBE    8192
#define PROBE_STRIDE 128
#define OFF_FLAGS    40960
#define FLAG_STRIDE  256
#define OFF_HB       73728
#define HB_STRIDE    32768

#define DYN_LDS      (88 * 1024)   // forces 1 block/CU (160KB LDS pool)

typedef __bf16 bf16_t;
typedef __bf16 bf16x8 __attribute__((ext_vector_type(8)));
typedef float  f32x4  __attribute__((ext_vector_type(4)));
typedef float  f32x2  __attribute__((ext_vector_type(2)));
typedef unsigned uint4v __attribute__((ext_vector_type(4)));

__device__ __forceinline__ unsigned pack_bf16(float a, float b) {
    unsigned short lo = __builtin_bit_cast(unsigned short, (bf16_t)a);
    unsigned short hi = __builtin_bit_cast(unsigned short, (bf16_t)b);
    return (unsigned)lo | ((unsigned)hi << 16);
}

// Device-wide barrier with release/acquire agent fences (wbl2 / inv).
__device__ __forceinline__ void device_barrier(int* arrive, int bid, int tid, int target) {
    __builtin_amdgcn_fence(__ATOMIC_RELEASE, "agent");
    __syncthreads();
    if (tid < 64) {
        if (tid == 0)
            __hip_atomic_store(&arrive[bid], target, __ATOMIC_RELAXED, __HIP_MEMORY_SCOPE_AGENT);
        for (;;) {
            int v0 = __hip_atomic_load(&arrive[tid],       __ATOMIC_RELAXED, __HIP_MEMORY_SCOPE_AGENT);
            int v1 = __hip_atomic_load(&arrive[tid + 64],  __ATOMIC_RELAXED, __HIP_MEMORY_SCOPE_AGENT);
            int v2 = __hip_atomic_load(&arrive[tid + 128], __ATOMIC_RELAXED, __HIP_MEMORY_SCOPE_AGENT);
            int v3 = __hip_atomic_load(&arrive[tid + 192], __ATOMIC_RELAXED, __HIP_MEMORY_SCOPE_AGENT);
            if (__all((v0 >= target) & (v1 >= target) & (v2 >= target) & (v3 >= target))) break;
            __builtin_amdgcn_s_sleep(1);
        }
    }
    __syncthreads();
    __builtin_amdgcn_fence(__ATOMIC_ACQUIRE, "agent");
}

// LOCAL=true : plain store (write-through L1 -> XCD L2) + sc0 load (L1
//              bypass, reads XCD L2). Probe-validated before use.
// LOCAL=false: sc0 sc1 both ways (L3 coherence point) - R3's protocol.
template<bool LOCAL>
__device__ __forceinline__ void ld16(uint4v& r, const bf16_t* p) {
    if constexpr (LOCAL)
        asm volatile("global_load_dwordx4 %0, %1, off sc0" : "=&v"(r) : "v"(p) : "memory");
    else
        asm volatile("global_load_dwordx4 %0, %1, off sc0 sc1" : "=&v"(r) : "v"(p) : "memory");
}
template<bool LOCAL>
__device__ __forceinline__ void st32(void* p, unsigned v) {
    if constexpr (LOCAL)
        asm volatile("global_store_dword %0, %1, off" :: "v"(p), "v"(v) : "memory");
    else
        asm volatile("global_store_dword %0, %1, off sc0 sc1" :: "v"(p), "v"(v) : "memory");
}
template<bool LOCAL>
__device__ __forceinline__ int ldflag(const int* p) {
    int v;
    if constexpr (LOCAL)
        asm volatile("global_load_dword %0, %1, off sc0\n\ts_waitcnt vmcnt(0)"
                     : "=&v"(v) : "v"(p) : "memory");
    else
        asm volatile("global_load_dword %0, %1, off sc0 sc1\n\ts_waitcnt vmcnt(0)"
                     : "=&v"(v) : "v"(p) : "memory");
    return v;
}

template<bool LOCAL>
__device__ __forceinline__ void scan_loop(
    uint4v (&breg)[17],
    const bf16_t* Ab0, const bf16_t* Ab1,
    bf16_t* buf0, bf16_t* buf1,
    int* flags, int slot, int h0,
    const float* xp, int xb, int xd,
    float* outp, float bias_c,
    float* lds, int tid, int lane, int wv)
{
    const int quad = lane >> 4;
    const int mcol = lane & 15;
    const int fb   = (tid >> 5) & 3;
    const int fcw  = tid & 31;
    const int fn   = fcw >> 4, fcc = fcw & 15;
    int*       myflag = flags + slot;           // dense: one int per slot
    const int* pollp  = flags + (lane & 31);    // lanes 0-31 cover the line
    float hp = 0.f;

    #pragma unroll 1
    for (int t = 0; t < T_; ++t) {
        const bf16_t* Ab   = (t & 1) ? Ab1 : Ab0;
        bf16_t*       nxtb = (t & 1) ? buf0 : buf1;

        // x_{t+1} prefetch (slot-0 block, waves 2-3): latency hides under
        // the A-load + MFMA phase.
        f32x2 xv = {0.f, 0.f};
        const bool doX = (slot == 0) && (tid >= 128) && (t + 1 < T_);
        if (doX)
            asm volatile("global_load_dwordx2 %0, %1, off" : "=v"(xv) : "v"(xp) : "memory");

        // A-fragments: 17 back-to-back 16B loads -> one L2 (LOCAL) / L3 RT.
        uint4v a0,a1,a2,a3,a4,a5,a6,a7,a8,a9,a10,a11,a12,a13,a14,a15,a16;
        ld16<LOCAL>(a0,  Ab +  0*32); ld16<LOCAL>(a1,  Ab +  1*32);
        ld16<LOCAL>(a2,  Ab +  2*32); ld16<LOCAL>(a3,  Ab +  3*32);
        ld16<LOCAL>(a4,  Ab +  4*32); ld16<LOCAL>(a5,  Ab +  5*32);
        ld16<LOCAL>(a6,  Ab +  6*32); ld16<LOCAL>(a7,  Ab +  7*32);
        ld16<LOCAL>(a8,  Ab +  8*32); ld16<LOCAL>(a9,  Ab +  9*32);
        ld16<LOCAL>(a10, Ab + 10*32); ld16<LOCAL>(a11, Ab + 11*32);
        ld16<LOCAL>(a12, Ab + 12*32); ld16<LOCAL>(a13, Ab + 13*32);
        ld16<LOCAL>(a14, Ab + 14*32); ld16<LOCAL>(a15, Ab + 15*32);
        ld16<LOCAL>(a16, Ab + 16*32);
        asm volatile("s_waitcnt vmcnt(0)"
                     : "+v"(a0),"+v"(a1),"+v"(a2),"+v"(a3),"+v"(a4),"+v"(a5),
                       "+v"(a6),"+v"(a7),"+v"(a8),"+v"(a9),"+v"(a10),"+v"(a11),
                       "+v"(a12),"+v"(a13),"+v"(a14),"+v"(a15),"+v"(a16),
                       "+v"(xv)
                     :: "memory");

        // 17 MFMA, 4 interleaved accumulator chains.
        f32x4 acc0 = {0.f,0.f,0.f,0.f}, acc1 = acc0, acc2 = acc0, acc3 = acc0;
        #define AM(reg, idx, acc) \
            acc = __builtin_amdgcn_mfma_f32_16x16x32_bf16( \
                __builtin_bit_cast(bf16x8, reg), \
                __builtin_bit_cast(bf16x8, breg[idx]), acc, 0, 0, 0);
        AM(a0,0,acc0)   AM(a1,1,acc1)   AM(a2,2,acc2)   AM(a3,3,acc3)
        AM(a4,4,acc0)   AM(a5,5,acc1)   AM(a6,6,acc2)   AM(a7,7,acc3)
        AM(a8,8,acc0)   AM(a9,9,acc1)   AM(a10,10,acc2) AM(a11,11,acc3)
        AM(a12,12,acc0) AM(a13,13,acc1) AM(a14,14,acc2) AM(a15,15,acc3)
        AM(a16,16,acc0)
        #undef AM
        f32x4 acc = (acc0 + acc1) + (acc2 + acc3);

        // Cross-wave K-half reduce via LDS. C/D: col=lane&15, row=quad*4+i.
        #pragma unroll
        for (int i = 0; i < 4; ++i)
            lds[wv * 256 + (quad * 4 + i) * 16 + mcol] = acc[i];
        __syncthreads();

        float hn = 0.f;
        if (tid < 128) {
            // wave (n_=fn,kh=0) = region fn; wave (n_=fn,kh=1) = region fn+2
            float s  = lds[fn * 256 + fb * 16 + fcc]
                     + lds[(fn + 2) * 256 + fb * 16 + fcc];
            float u  = s + bias_c;
            hn = (1.f - LRATE) * hp + LRATE * tanhf(u);
            hp = hn;
            unsigned hbits = (unsigned)__builtin_bit_cast(unsigned short, (bf16_t)hn);
            unsigned hi    = __shfl_down(hbits, 1);
            if (!(tid & 1))
                st32<LOCAL>(nxtb + fb * RLEN + h0 + fcw, hbits | (hi << 16));
        } else if (doX) {
            st32<LOCAL>(nxtb + xb * RLEN + H_ + xd, pack_bf16(xv[0], xv[1]));
            xp += D_;
        }

        if (t + 1 < T_) {
            // Drain h/x stores (ack from coherence point), then publish.
            asm volatile("s_waitcnt vmcnt(0)" ::: "memory");
            __syncthreads();
            if (tid == 0)
                st32<LOCAL>(myflag, (unsigned)(t + 1));
            if (tid < 128) outp[(size_t)t * H_] = hn;   // off critical path
            const int target = t + 1;
            for (;;) {
                int v = ldflag<LOCAL>(pollp);
                if (__all(v >= target)) break;
            }
        } else {
            if (tid < 128) outp[(size_t)t * H_] = hn;
        }
    }
}

__global__ __launch_bounds__(NTHR, 2) void esn_scan(
    const float* __restrict__ x,     // [B, T, D]
    const float* __restrict__ Win,   // [H, D]
    const float* __restrict__ bias,  // [H]
    const float* __restrict__ W,     // [H, H]
    float* __restrict__ out,         // [B, T, H]
    unsigned char* wsb)
{
    extern __shared__ unsigned char dynsmem[];   // occupancy ballast (88KB)
    __shared__ float lds[1024];
    __shared__ int slot_sh;
    (void)dynsmem;

    int* darr = (int*)wsb;
    int* cnt  = (int*)(wsb + OFF_CNT);
    int* badp = (int*)(wsb + OFF_BAD);

    unsigned xcd;
    asm volatile("s_getreg_b32 %0, hwreg(HW_REG_XCC_ID)" : "=s"(xcd));
    xcd &= 7;

    const int tid  = threadIdx.x;
    const int bid  = blockIdx.x;
    const int lane = tid & 63;
    const int wv   = tid >> 6;

    if (tid == 0) slot_sh = atomicAdd(&cnt[xcd], 1);
    __syncthreads();
    const int slot_raw = slot_sh;

    device_barrier(darr, bid, tid, 1);

    // Symmetry: did every XCD get exactly 32 blocks? (Deterministic when
    // the 88KB-LDS coop launch succeeded: 1 block/CU, 256 CUs = 8x32.)
    bool sym;
    {
        int c = __hip_atomic_load(&cnt[lane & 7], __ATOMIC_RELAXED, __HIP_MEMORY_SCOPE_AGENT);
        sym = __all(c == NSLOT);
    }
    const int g  = sym ? (int)xcd : (bid & 7);
    const int s  = sym ? slot_raw : (bid >> 3);
    const int h0 = s * 32;

    // ---- LOCAL-coherence probe (only when placement is symmetric) ----
    // Ring within the XCD: (g,s) produces, (g,s-1) consumes. Two rounds;
    // round 2 re-reads the same lines (catches stale-clean L2 copies).
    // Bounded polls (8k iters ~ <=0.4ms) => never deadlocks.
    if (sym && tid == 0) {
        unsigned* pd = (unsigned*)(wsb + OFF_PROBE + ((size_t)g * 32 + s) * PROBE_STRIDE);
        unsigned* pf = pd + 16;   // +64B
        unsigned* nd = (unsigned*)(wsb + OFF_PROBE + ((size_t)g * 32 + ((s + 1) & 31)) * PROBE_STRIDE);
        unsigned* nf = nd + 16;
        int bad = 0;
        for (int round = 1; round <= 2 && !bad; ++round) {
            unsigned val = 0xA5000000u + ((unsigned)round << 16) + (unsigned)s;
            st32<true>(pd + (round & 1), val);
            asm volatile("s_waitcnt vmcnt(0)" ::: "memory");
            st32<true>(pf, (unsigned)round);
            unsigned fv = 0; int iters = 0;
            for (;;) {
                fv = (unsigned)ldflag<true>((const int*)nf);
                if (fv >= (unsigned)round) break;
                if (++iters > 8192) { bad = 1; break; }
            }
            if (!bad) {
                unsigned dv = (unsigned)ldflag<true>((const int*)(nd + (round & 1)));
                unsigned expect = 0xA5000000u + ((unsigned)round << 16) + (unsigned)((s + 1) & 31);
                if (dv != expect) bad = 1;
            }
        }
        if (bad) atomicOr(badp, 1);
    }

    device_barrier(darr, bid, tid, 2);

    int badv = __hip_atomic_load(badp, __ATOMIC_RELAXED, __HIP_MEMORY_SCOPE_AGENT);
    const bool local = sym && (badv == 0);

    int*    flags = (int*)(wsb + OFF_FLAGS + (size_t)g * FLAG_STRIDE);
    bf16_t* hb    = (bf16_t*)(wsb + OFF_HB + (size_t)g * HB_STRIDE);
    bf16_t* buf0  = hb;
    bf16_t* buf1  = hb + BUFE;

    // ---------------- init ----------------
    // Zero buf0 h-region (rows 0-3, k<1024) + zero-row 4 of BOTH buffers.
    {
        unsigned* hb32 = (unsigned*)hb;              // u32 view, row stride 544
        unsigned gi = (unsigned)s * NTHR + tid;
        if (gi < 2048)            hb32[(gi >> 9) * 544 + (gi & 511)] = 0;
        else if (gi < 2592)       hb32[4 * 544 + (gi - 2048)] = 0;
        else if (gi < 3136)       hb32[2720 + 4 * 544 + (gi - 2592)] = 0;
        if (s == 0) {             // stage x_0 into buf0 x-region
            int b = tid >> 6, d = tid & 63;
            float v = x[(size_t)(4 * g + b) * (T_ * D_) + d];
            hb[b * RLEN + H_ + d] = (bf16_t)v;
        }
    }

    // B-fragments: W rows [h0,h0+32) (+ Win for k>=1024), bf16, registers.
    const int n_   = wv & 1;          // N-tile (16 cols)
    const int kh   = wv >> 1;         // K half [kh*544, kh*544+544)
    const int quad = lane >> 4;
    const int mcol = lane & 15;
    const int col  = h0 + n_ * 16 + mcol;

    uint4v breg[17];
    for (int kc = 0; kc < 17; ++kc) {
        int kb = kh * 544 + kc * 32 + quad * 8;
        float v[8];
        #pragma unroll
        for (int j = 0; j < 8; ++j) {
            int k = kb + j;
            v[j] = (k < H_) ? W[(size_t)col * H_ + k]
                            : Win[col * D_ + (k - H_)];
        }
        uint4v p;
        p[0] = pack_bf16(v[0], v[1]); p[1] = pack_bf16(v[2], v[3]);
        p[2] = pack_bf16(v[4], v[5]); p[3] = pack_bf16(v[6], v[7]);
        breg[kc] = p;
    }

    // A-fragment base: row = batch (lane&15), rows >=4 clamp to zero-row 4.
    const int r    = mcol;
    const int rr   = (r < 4) ? r : 4;
    const int aoff = rr * RLEN + kh * 544 + quad * 8;
    const bf16_t* Ab0 = buf0 + aoff;
    const bf16_t* Ab1 = buf1 + aoff;

    // Finisher state (waves 0-1): one (batch, col) per thread.
    const int fb  = (tid >> 5) & 3;
    const int fcw = tid & 31;
    const float bias_c = bias[h0 + fcw];
    float* outp = out + (size_t)(4 * g + fb) * (T_ * H_) + h0 + fcw;

    // x-prefetch state (slot-0 block, waves 2-3): 2 floats/thread/step.
    const int t2 = tid & 127;
    const int xb = t2 >> 5, xd = (t2 & 31) * 2;
    const float* xp = x + (size_t)(4 * g + xb) * (T_ * D_) + D_ + xd; // t=1

    device_barrier(darr, bid, tid, 3);   // flushes init stores (wbl2)

    // ---------------- scan ----------------
    if (local)
        scan_loop<true >(breg, Ab0, Ab1, buf0, buf1, flags, s, h0,
                         xp, xb, xd, outp, bias_c, lds, tid, lane, wv);
    else
        scan_loop<false>(breg, Ab0, Ab1, buf0, buf1, flags, s, h0,
                         xp, xb, xd, outp, bias_c, lds, tid, lane, wv);
}

extern "C" void kernel_launch(void* const* d_in, const int* in_sizes, int n_in,
                              void* d_out, int out_size, void* d_ws, size_t ws_size,
                              hipStream_t stream) {
    (void)in_sizes; (void)n_in; (void)out_size; (void)ws_size;
    const float* x    = (const float*)d_in[0];
    const float* Win  = (const float*)d_in[1];
    const float* bias = (const float*)d_in[2];
    const float* W    = (const float*)d_in[3];
    float*       out  = (float*)d_out;
    void*        ws   = d_ws;

    static int attr_ok = -1;
    if (attr_ok < 0) {
        hipError_t ae = hipFuncSetAttribute((const void*)esn_scan,
                            hipFuncAttributeMaxDynamicSharedMemorySize, DYN_LDS);
        attr_ok = (ae == hipSuccess) ? 1 : 0;
    }

    void* args[] = { (void*)&x, (void*)&Win, (void*)&bias, (void*)&W, (void*)&out, (void*)&ws };
    hipError_t e = hipErrorUnknown;
    if (attr_ok == 1)
        e = hipLaunchCooperativeKernel((const void*)esn_scan, dim3(GRID), dim3(NTHR),
                                       args, DYN_LDS, stream);
    if (e != hipSuccess)
        e = hipLaunchCooperativeKernel((const void*)esn_scan, dim3(GRID), dim3(NTHR),
                                       args, 0, stream);
    if (e != hipSuccess)
        hipLaunchKernelGGL(esn_scan, dim3(GRID), dim3(NTHR), 0, stream,
                           x, Win, bias, W, out, (unsigned char*)ws);
}

// Round 5
// 2931.212 us; speedup vs baseline: 3.8641x; 1.0226x over previous
//
#include <hip/hip_runtime.h>
#include <hip/hip_bf16.h>

// ESN scan: h_{t+1} = 0.1*h_t + 0.9*tanh(x_t @ Win^T + b + h_t @ W^T)
// B=32, T=1000, D=64, H=1024.
//
// R8 = R7 (probe-validated XCD-local scan, PASSED 2.91us/step) + scheduling:
//  - x-straggler fix: R7 tied the slot-0 x HBM load into the A-load
//    vmcnt(0) -> ~600-900cy HBM latency gated slot-0's MFMAs each step and
//    the barrier spread it to the whole group. Now: 1-step-ahead pipeline
//    in ONE register: store x_{t+1} (loaded last step) at step TOP, reload
//    the same reg AFTER the A-loads, A-wait = vmcnt(1) for x-waves (x load
//    is the only outstanding op; in-order retirement makes count exact).
//    End-of-step drain skipped for x-waves (store retired at A-wait); the
//    poll's first vmcnt(1) retires the x load, making next step's store
//    safe. Empty asm "+v"(xcur) after the poll pins consumption order.
//  - 2-deep pipelined flag poll: two loads in flight, vmcnt(1)+check
//    oldest+reissue (cuts detect latency by ~1 poll iteration).
//  - fast tanh: 1 - 2*rcp(e^{2u}+1) (abs err ~1e-6 << 0.02 threshold;
//    correct saturation at +-inf), replaces branchy libm tanhf.
// Everything else (grouping, probe, fallback, layout, launch ladder)
// identical to R7.

#define B_    32
#define T_    1000
#define D_    64
#define H_    1024
#define GRID  256
#define NTHR  256
#define LRATE 0.9f
#define NSLOT 32

#define ROWS  5              // 4 batch rows + 1 zero row (A rows 4..15)
#define RLEN  1088           // K extent: 1024 h + 64 x
#define BUFE  (ROWS * RLEN)  // 5440 bf16 per buffer

// ws layout (harness memsets ws each dispatch):
//   [0,1024)        device barrier arrive flags (256 ints)
//   [1024,1056)     per-XCD block counters (8 ints)
//   [1056,1060)     badflag (probe verdict)
//   [8192,40960)    probe region: (g*32+slot)*128B {data[2] @+0, flag @+64}
//   [40960,43008)   per-group flag lines: 32 ints dense, 256B stride
//   [73728,335872)  per-group h buffers: 2*5440*2B, stride 32768
#define OFF_CNT      1024
#define OFF_BAD      1056
#define OFF_PROBE    8192
#define PROBE_STRIDE 128
#define OFF_FLAGS    40960
#define FLAG_STRIDE  256
#define OFF_HB       73728
#define HB_STRIDE    32768

#define DYN_LDS      (88 * 1024)   // forces 1 block/CU (160KB LDS pool)

typedef __bf16 bf16_t;
typedef __bf16 bf16x8 __attribute__((ext_vector_type(8)));
typedef float  f32x4  __attribute__((ext_vector_type(4)));
typedef float  f32x2  __attribute__((ext_vector_type(2)));
typedef unsigned uint4v __attribute__((ext_vector_type(4)));

__device__ __forceinline__ unsigned pack_bf16(float a, float b) {
    unsigned short lo = __builtin_bit_cast(unsigned short, (bf16_t)a);
    unsigned short hi = __builtin_bit_cast(unsigned short, (bf16_t)b);
    return (unsigned)lo | ((unsigned)hi << 16);
}

// Device-wide barrier with release/acquire agent fences (wbl2 / inv).
__device__ __forceinline__ void device_barrier(int* arrive, int bid, int tid, int target) {
    __builtin_amdgcn_fence(__ATOMIC_RELEASE, "agent");
    __syncthreads();
    if (tid < 64) {
        if (tid == 0)
            __hip_atomic_store(&arrive[bid], target, __ATOMIC_RELAXED, __HIP_MEMORY_SCOPE_AGENT);
        for (;;) {
            int v0 = __hip_atomic_load(&arrive[tid],       __ATOMIC_RELAXED, __HIP_MEMORY_SCOPE_AGENT);
            int v1 = __hip_atomic_load(&arrive[tid + 64],  __ATOMIC_RELAXED, __HIP_MEMORY_SCOPE_AGENT);
            int v2 = __hip_atomic_load(&arrive[tid + 128], __ATOMIC_RELAXED, __HIP_MEMORY_SCOPE_AGENT);
            int v3 = __hip_atomic_load(&arrive[tid + 192], __ATOMIC_RELAXED, __HIP_MEMORY_SCOPE_AGENT);
            if (__all((v0 >= target) & (v1 >= target) & (v2 >= target) & (v3 >= target))) break;
            __builtin_amdgcn_s_sleep(1);
        }
    }
    __syncthreads();
    __builtin_amdgcn_fence(__ATOMIC_ACQUIRE, "agent");
}

// LOCAL=true : plain store (write-through L1 -> XCD L2) + sc0 load (L1
//              bypass, reads XCD L2). Probe-validated before use.
// LOCAL=false: sc0 sc1 both ways (L3 coherence point) - R3's protocol.
template<bool LOCAL>
__device__ __forceinline__ void ld16(uint4v& r, const bf16_t* p) {
    if constexpr (LOCAL)
        asm volatile("global_load_dwordx4 %0, %1, off sc0" : "=&v"(r) : "v"(p) : "memory");
    else
        asm volatile("global_load_dwordx4 %0, %1, off sc0 sc1" : "=&v"(r) : "v"(p) : "memory");
}
template<bool LOCAL>
__device__ __forceinline__ void st32(void* p, unsigned v) {
    if constexpr (LOCAL)
        asm volatile("global_store_dword %0, %1, off" :: "v"(p), "v"(v) : "memory");
    else
        asm volatile("global_store_dword %0, %1, off sc0 sc1" :: "v"(p), "v"(v) : "memory");
}
template<bool LOCAL>
__device__ __forceinline__ int ldflag(const int* p) {
    int v;
    if constexpr (LOCAL)
        asm volatile("global_load_dword %0, %1, off sc0\n\ts_waitcnt vmcnt(0)"
                     : "=&v"(v) : "v"(p) : "memory");
    else
        asm volatile("global_load_dword %0, %1, off sc0 sc1\n\ts_waitcnt vmcnt(0)"
                     : "=&v"(v) : "v"(p) : "memory");
    return v;
}

template<bool LOCAL>
__device__ __forceinline__ void scan_loop(
    uint4v (&breg)[17],
    const bf16_t* Ab0, const bf16_t* Ab1,
    bf16_t* buf0, bf16_t* buf1,
    int* flags, int slot, int h0,
    f32x2 xcur,              // x_{t+1} data (preloaded slice 1; completed)
    const float* xq0,        // this thread's x pointer for slice t=2
    int xb, int xd,
    float* outp, float bias_c,
    float* lds, int tid, int lane, int wv)
{
    const int quad = lane >> 4;
    const int mcol = lane & 15;
    const int fb   = (tid >> 5) & 3;
    const int fcw  = tid & 31;
    const int fn   = fcw >> 4, fcc = fcw & 15;
    int*       myflag = flags + slot;           // dense: one int per slot
    const int* pollp  = flags + (lane & 31);    // lanes 0-31 cover the line
    const bool isx = (slot == 0) && (tid >= 128);   // wave-uniform
    const float* xq = xq0;
    float hp = 0.f;

    #pragma unroll 1
    for (int t = 0; t < T_; ++t) {
        const bf16_t* Ab   = (t & 1) ? Ab1 : Ab0;
        bf16_t*       nxtb = (t & 1) ? buf0 : buf1;

        // TOP: store x_{t+1} (value loaded >=1 step ago; completion assured
        // by previous step's poll vmcnt + "+v"(xcur) re-def). nxtb's x
        // region is dead until our flag publishes (consumers passed flag t).
        if (isx && (t + 1) < T_) {
            unsigned pk = pack_bf16(xcur[0], xcur[1]);
            st32<LOCAL>(nxtb + xb * RLEN + H_ + xd, pk);
        }

        // A-fragments: 17 back-to-back 16B loads -> one L2 (LOCAL) / L3 RT.
        uint4v a0,a1,a2,a3,a4,a5,a6,a7,a8,a9,a10,a11,a12,a13,a14,a15,a16;
        ld16<LOCAL>(a0,  Ab +  0*32); ld16<LOCAL>(a1,  Ab +  1*32);
        ld16<LOCAL>(a2,  Ab +  2*32); ld16<LOCAL>(a3,  Ab +  3*32);
        ld16<LOCAL>(a4,  Ab +  4*32); ld16<LOCAL>(a5,  Ab +  5*32);
        ld16<LOCAL>(a6,  Ab +  6*32); ld16<LOCAL>(a7,  Ab +  7*32);
        ld16<LOCAL>(a8,  Ab +  8*32); ld16<LOCAL>(a9,  Ab +  9*32);
        ld16<LOCAL>(a10, Ab + 10*32); ld16<LOCAL>(a11, Ab + 11*32);
        ld16<LOCAL>(a12, Ab + 12*32); ld16<LOCAL>(a13, Ab + 13*32);
        ld16<LOCAL>(a14, Ab + 14*32); ld16<LOCAL>(a15, Ab + 15*32);
        ld16<LOCAL>(a16, Ab + 16*32);

        // x_{t+2} load, issued LAST so vmcnt(1) below waits exactly the
        // A-loads (in-order retirement) while x rides out under MFMA+poll.
        const bool ldx = isx && (t + 2) < T_;
        if (ldx) {
            asm volatile("global_load_dwordx2 %0, %1, off"
                         : "=v"(xcur) : "v"(xq) : "memory");
            xq += D_;
        }

        #define AWAIT(N) asm volatile("s_waitcnt vmcnt(" #N ")" \
            : "+v"(a0),"+v"(a1),"+v"(a2),"+v"(a3),"+v"(a4),"+v"(a5), \
              "+v"(a6),"+v"(a7),"+v"(a8),"+v"(a9),"+v"(a10),"+v"(a11), \
              "+v"(a12),"+v"(a13),"+v"(a14),"+v"(a15),"+v"(a16) :: "memory")
        if (ldx) { AWAIT(1); } else { AWAIT(0); }
        #undef AWAIT

        // 17 MFMA, 4 interleaved accumulator chains.
        f32x4 acc0 = {0.f,0.f,0.f,0.f}, acc1 = acc0, acc2 = acc0, acc3 = acc0;
        #define AM(reg, idx, acc) \
            acc = __builtin_amdgcn_mfma_f32_16x16x32_bf16( \
                __builtin_bit_cast(bf16x8, reg), \
                __builtin_bit_cast(bf16x8, breg[idx]), acc, 0, 0, 0);
        AM(a0,0,acc0)   AM(a1,1,acc1)   AM(a2,2,acc2)   AM(a3,3,acc3)
        AM(a4,4,acc0)   AM(a5,5,acc1)   AM(a6,6,acc2)   AM(a7,7,acc3)
        AM(a8,8,acc0)   AM(a9,9,acc1)   AM(a10,10,acc2) AM(a11,11,acc3)
        AM(a12,12,acc0) AM(a13,13,acc1) AM(a14,14,acc2) AM(a15,15,acc3)
        AM(a16,16,acc0)
        #undef AM
        f32x4 acc = (acc0 + acc1) + (acc2 + acc3);

        // Cross-wave K-half reduce via LDS. C/D: col=lane&15, row=quad*4+i.
        #pragma unroll
        for (int i = 0; i < 4; ++i)
            lds[wv * 256 + (quad * 4 + i) * 16 + mcol] = acc[i];
        __syncthreads();

        float hn = 0.f;
        if (tid < 128) {
            // wave (n_=fn,kh=0) = region fn; wave (n_=fn,kh=1) = region fn+2
            float s  = lds[fn * 256 + fb * 16 + fcc]
                     + lds[(fn + 2) * 256 + fb * 16 + fcc];
            float u  = s + bias_c;
            // tanh(u) = 1 - 2/(e^{2u}+1); saturates correctly at +-inf.
            float ex = __expf(2.f * u);
            float th = 1.f - 2.f * __builtin_amdgcn_rcpf(ex + 1.f);
            hn = (1.f - LRATE) * hp + LRATE * th;
            hp = hn;
            unsigned hbits = (unsigned)__builtin_bit_cast(unsigned short, (bf16_t)hn);
            unsigned hi    = __shfl_down(hbits, 1);
            if (!(tid & 1))
                st32<LOCAL>(nxtb + fb * RLEN + h0 + fcw, hbits | (hi << 16));
        }

        if (t + 1 < T_) {
            // Drain h-store acks. x-waves with an in-flight x load skip it:
            // their x-store already retired at the A-wait vmcnt(1).
            if (!ldx) asm volatile("s_waitcnt vmcnt(0)" ::: "memory");
            __syncthreads();
            if (tid == 0)
                st32<LOCAL>(myflag, (unsigned)(t + 1));
            if (tid < 128) outp[(size_t)t * H_] = hn;   // off critical path
            // 2-deep pipelined poll: two loads in flight, vmcnt(1) + check
            // oldest + reissue. In-order retirement makes counts exact even
            // with flag/out stores or the x load still pending (they are
            // older and retire first).
            const int target = t + 1;
            int v0 = 0, v1 = 0;
            #define PLD(r) do { if constexpr (LOCAL) \
                    asm volatile("global_load_dword %0, %1, off sc0" \
                                 : "=v"(r) : "v"(pollp) : "memory"); \
                else \
                    asm volatile("global_load_dword %0, %1, off sc0 sc1" \
                                 : "=v"(r) : "v"(pollp) : "memory"); } while (0)
            PLD(v0); PLD(v1);
            for (;;) {
                asm volatile("s_waitcnt vmcnt(1)" : "+v"(v0) :: "memory");
                if (__all(v0 >= target)) break;
                PLD(v0);
                asm volatile("s_waitcnt vmcnt(1)" : "+v"(v1) :: "memory");
                if (__all(v1 >= target)) break;
                PLD(v1);
            }
            #undef PLD
            // Re-def xcur after the poll: any consumer (next step's pack/
            // store) is ordered after these waits -> x load is complete.
            asm volatile("" : "+v"(xcur) :: );
        } else {
            if (tid < 128) outp[(size_t)t * H_] = hn;
        }
    }
}

__global__ __launch_bounds__(NTHR, 2) void esn_scan(
    const float* __restrict__ x,     // [B, T, D]
    const float* __restrict__ Win,   // [H, D]
    const float* __restrict__ bias,  // [H]
    const float* __restrict__ W,     // [H, H]
    float* __restrict__ out,         // [B, T, H]
    unsigned char* wsb)
{
    extern __shared__ unsigned char dynsmem[];   // occupancy ballast (88KB)
    __shared__ float lds[1024];
    __shared__ int slot_sh;
    (void)dynsmem;

    int* darr = (int*)wsb;
    int* cnt  = (int*)(wsb + OFF_CNT);
    int* badp = (int*)(wsb + OFF_BAD);

    unsigned xcd;
    asm volatile("s_getreg_b32 %0, hwreg(HW_REG_XCC_ID)" : "=s"(xcd));
    xcd &= 7;

    const int tid  = threadIdx.x;
    const int bid  = blockIdx.x;
    const int lane = tid & 63;
    const int wv   = tid >> 6;

    if (tid == 0) slot_sh = atomicAdd(&cnt[xcd], 1);
    __syncthreads();
    const int slot_raw = slot_sh;

    device_barrier(darr, bid, tid, 1);

    // Symmetry: did every XCD get exactly 32 blocks? (Deterministic when
    // the 88KB-LDS coop launch succeeded: 1 block/CU, 256 CUs = 8x32.)
    bool sym;
    {
        int c = __hip_atomic_load(&cnt[lane & 7], __ATOMIC_RELAXED, __HIP_MEMORY_SCOPE_AGENT);
        sym = __all(c == NSLOT);
    }
    const int g  = sym ? (int)xcd : (bid & 7);
    const int s  = sym ? slot_raw : (bid >> 3);
    const int h0 = s * 32;

    // ---- LOCAL-coherence probe (only when placement is symmetric) ----
    if (sym && tid == 0) {
        unsigned* pd = (unsigned*)(wsb + OFF_PROBE + ((size_t)g * 32 + s) * PROBE_STRIDE);
        unsigned* pf = pd + 16;   // +64B
        unsigned* nd = (unsigned*)(wsb + OFF_PROBE + ((size_t)g * 32 + ((s + 1) & 31)) * PROBE_STRIDE);
        unsigned* nf = nd + 16;
        int bad = 0;
        for (int round = 1; round <= 2 && !bad; ++round) {
            unsigned val = 0xA5000000u + ((unsigned)round << 16) + (unsigned)s;
            st32<true>(pd + (round & 1), val);
            asm volatile("s_waitcnt vmcnt(0)" ::: "memory");
            st32<true>(pf, (unsigned)round);
            unsigned fv = 0; int iters = 0;
            for (;;) {
                fv = (unsigned)ldflag<true>((const int*)nf);
                if (fv >= (unsigned)round) break;
                if (++iters > 8192) { bad = 1; break; }
            }
            if (!bad) {
                unsigned dv = (unsigned)ldflag<true>((const int*)(nd + (round & 1)));
                unsigned expect = 0xA5000000u + ((unsigned)round << 16) + (unsigned)((s + 1) & 31);
                if (dv != expect) bad = 1;
            }
        }
        if (bad) atomicOr(badp, 1);
    }

    device_barrier(darr, bid, tid, 2);

    int badv = __hip_atomic_load(badp, __ATOMIC_RELAXED, __HIP_MEMORY_SCOPE_AGENT);
    const bool local = sym && (badv == 0);

    int*    flags = (int*)(wsb + OFF_FLAGS + (size_t)g * FLAG_STRIDE);
    bf16_t* hb    = (bf16_t*)(wsb + OFF_HB + (size_t)g * HB_STRIDE);
    bf16_t* buf0  = hb;
    bf16_t* buf1  = hb + BUFE;

    // ---------------- init ----------------
    // Zero buf0 h-region (rows 0-3, k<1024) + zero-row 4 of BOTH buffers.
    {
        unsigned* hb32 = (unsigned*)hb;              // u32 view, row stride 544
        unsigned gi = (unsigned)s * NTHR + tid;
        if (gi < 2048)            hb32[(gi >> 9) * 544 + (gi & 511)] = 0;
        else if (gi < 2592)       hb32[4 * 544 + (gi - 2048)] = 0;
        else if (gi < 3136)       hb32[2720 + 4 * 544 + (gi - 2592)] = 0;
        if (s == 0) {             // stage x_0 into buf0 x-region
            int b = tid >> 6, d = tid & 63;
            float v = x[(size_t)(4 * g + b) * (T_ * D_) + d];
            hb[b * RLEN + H_ + d] = (bf16_t)v;
        }
    }

    // B-fragments: W rows [h0,h0+32) (+ Win for k>=1024), bf16, registers.
    const int n_   = wv & 1;          // N-tile (16 cols)
    const int kh   = wv >> 1;         // K half [kh*544, kh*544+544)
    const int quad = lane >> 4;
    const int mcol = lane & 15;
    const int col  = h0 + n_ * 16 + mcol;

    uint4v breg[17];
    for (int kc = 0; kc < 17; ++kc) {
        int kb = kh * 544 + kc * 32 + quad * 8;
        float v[8];
        #pragma unroll
        for (int j = 0; j < 8; ++j) {
            int k = kb + j;
            v[j] = (k < H_) ? W[(size_t)col * H_ + k]
                            : Win[col * D_ + (k - H_)];
        }
        uint4v p;
        p[0] = pack_bf16(v[0], v[1]); p[1] = pack_bf16(v[2], v[3]);
        p[2] = pack_bf16(v[4], v[5]); p[3] = pack_bf16(v[6], v[7]);
        breg[kc] = p;
    }

    // A-fragment base: row = batch (lane&15), rows >=4 clamp to zero-row 4.
    const int r    = mcol;
    const int rr   = (r < 4) ? r : 4;
    const int aoff = rr * RLEN + kh * 544 + quad * 8;
    const bf16_t* Ab0 = buf0 + aoff;
    const bf16_t* Ab1 = buf1 + aoff;

    // Finisher state (waves 0-1): one (batch, col) per thread.
    const int fb  = (tid >> 5) & 3;
    const int fcw = tid & 31;
    const float bias_c = bias[h0 + fcw];
    float* outp = out + (size_t)(4 * g + fb) * (T_ * H_) + h0 + fcw;

    // x-pipeline state (slot-0 block, waves 2-3): 2 floats/thread/step.
    const int t2 = tid & 127;
    const int xb = t2 >> 5, xd = (t2 & 31) * 2;
    const float* xp = x + (size_t)(4 * g + xb) * (T_ * D_) + D_ + xd; // t=1

    // Preload x slice t=1 into the pipeline register (completed before the
    // barrier's release fence; first consumed at step 0's top store).
    f32x2 xcur = {0.f, 0.f};
    if (s == 0 && tid >= 128) {
        asm volatile("global_load_dwordx2 %0, %1, off" : "=v"(xcur) : "v"(xp) : "memory");
        asm volatile("s_waitcnt vmcnt(0)" : "+v"(xcur) :: "memory");
    }

    device_barrier(darr, bid, tid, 3);   // flushes init stores (wbl2)

    // ---------------- scan ----------------
    if (local)
        scan_loop<true >(breg, Ab0, Ab1, buf0, buf1, flags, s, h0,
                         xcur, xp + D_, xb, xd, outp, bias_c, lds, tid, lane, wv);
    else
        scan_loop<false>(breg, Ab0, Ab1, buf0, buf1, flags, s, h0,
                         xcur, xp + D_, xb, xd, outp, bias_c, lds, tid, lane, wv);
}

extern "C" void kernel_launch(void* const* d_in, const int* in_sizes, int n_in,
                              void* d_out, int out_size, void* d_ws, size_t ws_size,
                              hipStream_t stream) {
    (void)in_sizes; (void)n_in; (void)out_size; (void)ws_size;
    const float* x    = (const float*)d_in[0];
    const float* Win  = (const float*)d_in[1];
    const float* bias = (const float*)d_in[2];
    const float* W    = (const float*)d_in[3];
    float*       out  = (float*)d_out;
    void*        ws   = d_ws;

    static int attr_ok = -1;
    if (attr_ok < 0) {
        hipError_t ae = hipFuncSetAttribute((const void*)esn_scan,
                            hipFuncAttributeMaxDynamicSharedMemorySize, DYN_LDS);
        attr_ok = (ae == hipSuccess) ? 1 : 0;
    }

    void* args[] = { (void*)&x, (void*)&Win, (void*)&bias, (void*)&W, (void*)&out, (void*)&ws };
    hipError_t e = hipErrorUnknown;
    if (attr_ok == 1)
        e = hipLaunchCooperativeKernel((const void*)esn_scan, dim3(GRID), dim3(NTHR),
                                       args, DYN_LDS, stream);
    if (e != hipSuccess)
        e = hipLaunchCooperativeKernel((const void*)esn_scan, dim3(GRID), dim3(NTHR),
                                       args, 0, stream);
    if (e != hipSuccess)
        hipLaunchKernelGGL(esn_scan, dim3(GRID), dim3(NTHR), 0, stream,
                           x, Win, bias, W, out, (unsigned char*)ws);
}